// Round 6
// baseline (344.773 us; speedup 1.0000x reference)
//
#include <hip/hip_runtime.h>
#include <math.h>

// ---- NSA hyperparameters (compile-time, matches reference config) ----
constexpr int kT    = 2048;
constexpr int kHQ   = 16;
constexpr int kD    = 128;
constexpr int kKS   = 32;
constexpr int kST   = 16;
constexpr int kBS   = 64;
constexpr int kM    = (kT - kKS) / kST + 1;   // 127 compressed tokens
constexpr int kNB   = (kT + kBS - 1) / kBS;   // 32 selection blocks
constexpr int kTopN = 16;
constexpr int kNInit = 2;
constexpr int kWIN  = 512;
constexpr float kNEG = -1e30f;
constexpr float kScale = 0.08838834764831845f; // 128^-0.5

constexpr int kPad    = 32;
constexpr int kKBRows = kT + kPad; // 2080
constexpr int kVTCols = kT + kPad; // 2080

constexpr int kPSt = 72;    // P slab row stride (fp16)
constexpr int kPL  = 136;   // cmp p_lds row stride (bf16 shorts)
constexpr int kOC  = 36;    // ocmp stash lane stride (shorts; 72B, 8B-aligned)

typedef __attribute__((ext_vector_type(8))) short short8;
typedef __attribute__((ext_vector_type(4))) short short4v;
typedef __attribute__((ext_vector_type(8))) _Float16 half8;
typedef __attribute__((ext_vector_type(4))) _Float16 half4v;
typedef __attribute__((ext_vector_type(4))) float floatx4;

// RNE float -> bf16 bits
__device__ inline short f2bf(float x) {
    unsigned u = __float_as_uint(x);
    unsigned r = (u + 0x7fffu + ((u >> 16) & 1u)) >> 16;
    return (short)r;
}
__device__ inline float b2f(short h) {
    return __uint_as_float(((unsigned)(unsigned short)h) << 16);
}

// ---------------------------------------------------------------------
// K1: staging.  blocks [0,2080): bf16 K rows + fp16 V^T cols with the
// swapped-QK key permutation col = 4*(w&15) + (w>>4) (w = key mod 64).
// Pad rows (row >= kT) do NOT write vt (R3 lesson: perm overflows pad).
// blocks [2080,2208): mean-pool cmp_k as bf16 hi/lo planes + cmp V^T
// bf16 with the same permutation over m.  block=(128)
// ---------------------------------------------------------------------
__global__ void k_stage(const float* __restrict__ k, const float* __restrict__ v,
                        short* __restrict__ kb, _Float16* __restrict__ vt,
                        short* __restrict__ cmp_kh, short* __restrict__ cmp_kl,
                        short* __restrict__ cvt) {
    const int bid = blockIdx.x;
    const int d = threadIdx.x;
    if (bid < kKBRows) {
        const int row = bid;
        if (row < kT) {
            const int blk = row >> 6, w = row & 63;
            const int col = blk * kBS + 4 * (w & 15) + (w >> 4);
            kb[row * kD + d] = f2bf(k[(size_t)row * kD + d]);
            vt[(size_t)d * kVTCols + col] = (_Float16)v[(size_t)row * kD + d];
        } else {
            kb[row * kD + d] = 0;   // in-bounds, never read
        }
    } else {
        const int m = bid - kKBRows;        // 0..127 (>=kM = zero pad)
        float sk = 0.f, sv = 0.f;
        if (m < kM) {
            const int base = m * kST;
            #pragma unroll
            for (int i = 0; i < kKS; ++i) {
                sk += k[(size_t)(base + i) * kD + d];
                sv += v[(size_t)(base + i) * kD + d];
            }
            sk *= (1.0f / kKS);
            sv *= (1.0f / kKS);
        }
        const short hi = f2bf(sk);
        cmp_kh[m * kD + d] = hi;
        cmp_kl[m * kD + d] = f2bf(sk - b2f(hi));
        const int pc = (m & 64) + 4 * (m & 15) + ((m & 63) >> 4);
        cvt[d * 128 + pc] = f2bf(sv);
    }
}

// ---------------------------------------------------------------------
// Fused NSA kernel: one WAVE = one query t (grid=T, block=64, t=bid —
// balanced under stride-256 round-robin; R4 lesson).
// Phase A (cmp-attn): swapped-QK MFMA, bf16 hi/lo split, lane-local
//   softmax, butterfly slc_p, rank top-k in registers.  ocmp stashed to
//   LDS as bf16 (frees 32 VGPRs for Phase B — R5 spill lesson).
// Phase B: R4-proven inline body, single K buffer, no lambdas, no cap.
// Epilogue: merged single store reading the stash.
// ---------------------------------------------------------------------
__global__ void k_nsa(
        const float* __restrict__ q, const float* __restrict__ cw,
        const short* __restrict__ cmp_kh, const short* __restrict__ cmp_kl,
        const short* __restrict__ cvt, const short* __restrict__ kb,
        const _Float16* __restrict__ vt, float* __restrict__ out) {
    const int lane = threadIdx.x;
    const int l15 = lane & 15;
    const int quad = lane >> 4;
    const int t = blockIdx.x;

    __shared__ float sp[kNB];
    __shared__ short p_lds[16 * kPL];       // cmp P, bf16, perm cols
    __shared__ short ocst[64 * kOC];        // ocmp stash, bf16
    __shared__ _Float16 PS[16 * kPSt];
    __shared__ _Float16 PW[16 * kPSt];

    // ---- q head=l15, scaled, split hi/lo bf16 ----
    short8 qh[4], ql[4];
    {
        const float* qp = q + ((size_t)t * kHQ + l15) * kD + quad * 8;
        #pragma unroll
        for (int c = 0; c < 4; ++c) {
            const float4 f0 = *(const float4*)(qp + c * 32);
            const float4 f1 = *(const float4*)(qp + c * 32 + 4);
            const float xs[8] = {f0.x, f0.y, f0.z, f0.w, f1.x, f1.y, f1.z, f1.w};
            #pragma unroll
            for (int j = 0; j < 8; ++j) {
                const float x = xs[j] * kScale;
                const short h = f2bf(x);
                qh[c][j] = h;
                ql[c][j] = f2bf(x - b2f(h));
            }
        }
    }

    const int nvalid = (t >= kKS - 1) ? min(kM, (t - (kKS - 1)) / kST + 1) : 0;
    const int cur = t >> 6;

    // ================= Phase A: compressed attention =================
    unsigned selm;
    {
        floatx4 sacc[8];
        #pragma unroll
        for (int mt = 0; mt < 8; ++mt) {
            sacc[mt] = (floatx4){0, 0, 0, 0};
            const short* ah = cmp_kh + (mt * 16 + l15) * 128 + quad * 8;
            const short* al = cmp_kl + (mt * 16 + l15) * 128 + quad * 8;
            #pragma unroll
            for (int c = 0; c < 4; ++c) {
                const short8 Ah = *(const short8*)(ah + c * 32);
                const short8 Al = *(const short8*)(al + c * 32);
                sacc[mt] = __builtin_amdgcn_mfma_f32_16x16x32_bf16(Ah, qh[c], sacc[mt], 0, 0, 0);
                sacc[mt] = __builtin_amdgcn_mfma_f32_16x16x32_bf16(Ah, ql[c], sacc[mt], 0, 0, 0);
                sacc[mt] = __builtin_amdgcn_mfma_f32_16x16x32_bf16(Al, qh[c], sacc[mt], 0, 0, 0);
            }
        }
        // lane holds S[m = mt*16 + quad*4 + r][h = l15]
        float e[8][4];
        float mx = kNEG;
        #pragma unroll
        for (int mt = 0; mt < 8; ++mt)
            #pragma unroll
            for (int r = 0; r < 4; ++r) {
                const int m = mt * 16 + quad * 4 + r;
                const float s = (m < nvalid) ? sacc[mt][r] : kNEG;
                e[mt][r] = s;
                mx = fmaxf(mx, s);
            }
        mx = fmaxf(mx, __shfl_xor(mx, 16));
        mx = fmaxf(mx, __shfl_xor(mx, 32));
        float sum = 0.f;
        #pragma unroll
        for (int mt = 0; mt < 8; ++mt)
            #pragma unroll
            for (int r = 0; r < 4; ++r) {
                const int m = mt * 16 + quad * 4 + r;
                const float ev = (m < nvalid) ? __expf(e[mt][r] - mx) : 0.f;
                e[mt][r] = ev;
                sum += ev;
            }
        sum += __shfl_xor(sum, 16);
        sum += __shfl_xor(sum, 32);
        const float inv = (nvalid > 0) ? (1.f / sum) : 0.f;

        float Z[8], Y[8];
        #pragma unroll
        for (int mt = 0; mt < 8; ++mt) {
            const float p0 = e[mt][0] * inv, p1 = e[mt][1] * inv;
            const float p2 = e[mt][2] * inv, p3 = e[mt][3] * inv;
            e[mt][0] = p0; e[mt][1] = p1; e[mt][2] = p2; e[mt][3] = p3;
            Z[mt] = p0 + p1 + p2 + 0.5f * p3;
            Y[mt] = p3;
        }
        // p -> LDS (bf16, perm col = g*64 + 16*quad + 4*r + (mt&3))
        #pragma unroll
        for (int g = 0; g < 2; ++g)
            #pragma unroll
            for (int r = 0; r < 4; ++r) {
                short4v s4;
                s4[0] = f2bf(e[4 * g + 0][r]); s4[1] = f2bf(e[4 * g + 1][r]);
                s4[2] = f2bf(e[4 * g + 2][r]); s4[3] = f2bf(e[4 * g + 3][r]);
                *(short4v*)&p_lds[l15 * kPL + g * 64 + 16 * quad + 4 * r] = s4;
            }
        // butterfly h-sums (over l15 within each quad group)
        #pragma unroll
        for (int mt = 0; mt < 8; ++mt) {
            #pragma unroll
            for (int o = 1; o <= 8; o <<= 1) {
                Z[mt] += __shfl_xor(Z[mt], o, 16);
                Y[mt] += __shfl_xor(Y[mt], o, 16);
            }
        }
        // x[b = 4*mt + quad] = Z + 0.5 * Y(prev block)
        const int srcl = ((quad + 3) & 3) * 16 + l15;
        #pragma unroll
        for (int mt = 0; mt < 8; ++mt) {
            const float up  = __shfl(Y[mt], srcl);
            const float upm = __shfl(Y[(mt + 7) & 7], srcl);
            const float pv = quad ? up : (mt ? upm : 0.f);
            const int b = 4 * mt + quad;
            float x = Z[mt] + 0.5f * pv;
            if (b > cur) x = kNEG;
            if (b < kNInit || b == cur) x = 1e30f;
            if (l15 == 0) sp[b] = x;
        }
        // rank top-k (serial-argmax tie semantics; R4-proven)
        bool selp = false;
        if (lane < kNB) {
            const float xv = sp[lane];
            int rank = 0;
            #pragma unroll
            for (int b2 = 0; b2 < kNB; ++b2) {
                const float y = sp[b2];
                rank += (y > xv || (y == xv && b2 < lane)) ? 1 : 0;
            }
            selp = rank < kTopN;
        }
        selm = (unsigned)__ballot(selp);

        // cmp PV -> stash to LDS as bf16 (same-lane, no barrier needed)
        short8 ap[4];
        #pragma unroll
        for (int c = 0; c < 4; ++c)
            ap[c] = *(const short8*)&p_lds[l15 * kPL + c * 32 + quad * 8];
        #pragma unroll
        for (int nt = 0; nt < 8; ++nt) {
            floatx4 oc = (floatx4){0, 0, 0, 0};
            #pragma unroll
            for (int c = 0; c < 4; ++c) {
                const short8 bv = *(const short8*)(cvt + (size_t)(nt * 16 + l15) * 128 + c * 32 + quad * 8);
                oc = __builtin_amdgcn_mfma_f32_16x16x32_bf16(ap[c], bv, oc, 0, 0, 0);
            }
            short4v s4;
            s4[0] = f2bf(oc[0]); s4[1] = f2bf(oc[1]);
            s4[2] = f2bf(oc[2]); s4[3] = f2bf(oc[3]);
            *(short4v*)&ocst[lane * kOC + nt * 4] = s4;
        }
    }

    // ================= Phase B: select + SWA (R4-proven, inline) ======
    const int lob = max(0, (t - (kWIN - 1)) >> 6);
    const unsigned lm = 0xFFFFFFFFu >> (31 - cur);
    unsigned act = (selm & lm) | (lm & ~((1u << lob) - 1u));

    float mS = kNEG, lS = 0.f, mW = kNEG, lW = 0.f;
    floatx4 osel[8], oswa[8];
    #pragma unroll
    for (int n8 = 0; n8 < 8; ++n8) {
        osel[n8] = (floatx4){0, 0, 0, 0};
        oswa[n8] = (floatx4){0, 0, 0, 0};
    }

    while (act) {
        const int b = __builtin_ctz(act);
        act &= act - 1u;
        const bool bsel = (selm >> b) & 1u;
        const bool bswa = b >= lob;

        short8 kreg[4][4];
        {
            const short* kp = kb + (size_t)(b * kBS + l15) * kD + quad * 8;
            #pragma unroll
            for (int kt = 0; kt < 4; ++kt)
                #pragma unroll
                for (int c = 0; c < 4; ++c)
                    kreg[kt][c] = *(const short8*)(kp + kt * 16 * kD + c * 32);
        }
        half8 vreg[8][2];
        {
            const _Float16* vp = vt + (size_t)l15 * kVTCols + b * kBS + quad * 8;
            #pragma unroll
            for (int n8 = 0; n8 < 8; ++n8) {
                vreg[n8][0] = *(const half8*)(vp + (size_t)(n8 * 16) * kVTCols);
                vreg[n8][1] = *(const half8*)(vp + (size_t)(n8 * 16) * kVTCols + 32);
            }
        }

        floatx4 acc[4];
        #pragma unroll
        for (int kt = 0; kt < 4; ++kt) {
            acc[kt] = (floatx4){0, 0, 0, 0};
            #pragma unroll
            for (int c = 0; c < 4; ++c)
                acc[kt] = __builtin_amdgcn_mfma_f32_16x16x32_bf16(kreg[kt][c], qh[c], acc[kt], 0, 0, 0);
        }

        const int kbase = b * kBS + quad * 4;
        float bmS = kNEG, bmW = kNEG;
        #pragma unroll
        for (int kt = 0; kt < 4; ++kt)
            #pragma unroll
            for (int r = 0; r < 4; ++r) {
                const int key = kbase + kt * 16 + r;
                const float s = acc[kt][r];
                const bool ca = key <= t;
                const bool wi = ca && (t - key) < kWIN;
                if (ca) bmS = fmaxf(bmS, s);
                if (wi) bmW = fmaxf(bmW, s);
            }
        bmS = fmaxf(bmS, __shfl_xor(bmS, 16));
        bmS = fmaxf(bmS, __shfl_xor(bmS, 32));
        bmW = fmaxf(bmW, __shfl_xor(bmW, 16));
        bmW = fmaxf(bmW, __shfl_xor(bmW, 32));

        float aS = 1.f, aW = 1.f;
        float mSn = mS, mWn = mW;
        if (bsel) { mSn = fmaxf(mS, bmS); aS = __expf(mS - mSn); }
        if (bswa) { mWn = fmaxf(mW, bmW); aW = __expf(mW - mWn); }

        float sumS = 0.f, sumW = 0.f;
        if (bsel && bswa) {
            const float crv = __expf(mSn - mWn);
            #pragma unroll
            for (int r = 0; r < 4; ++r) {
                half4v hs, hw;
                #pragma unroll
                for (int kt = 0; kt < 4; ++kt) {
                    const int key = kbase + kt * 16 + r;
                    const bool ca = key <= t;
                    const bool wi = ca && (t - key) < kWIN;
                    const float e0 = ca ? __expf(acc[kt][r] - mSn) : 0.f;
                    const float e1 = wi ? e0 * crv : 0.f;
                    sumS += e0; sumW += e1;
                    hs[kt] = (_Float16)e0;
                    hw[kt] = (_Float16)e1;
                }
                *(half4v*)&PS[l15 * kPSt + 16 * quad + 4 * r] = hs;
                *(half4v*)&PW[l15 * kPSt + 16 * quad + 4 * r] = hw;
            }
        } else if (bsel) {
            #pragma unroll
            for (int r = 0; r < 4; ++r) {
                half4v hs;
                #pragma unroll
                for (int kt = 0; kt < 4; ++kt) {
                    const int key = kbase + kt * 16 + r;
                    const bool ca = key <= t;
                    const float e0 = ca ? __expf(acc[kt][r] - mSn) : 0.f;
                    sumS += e0;
                    hs[kt] = (_Float16)e0;
                }
                *(half4v*)&PS[l15 * kPSt + 16 * quad + 4 * r] = hs;
            }
        } else {
            #pragma unroll
            for (int r = 0; r < 4; ++r) {
                half4v hw;
                #pragma unroll
                for (int kt = 0; kt < 4; ++kt) {
                    const int key = kbase + kt * 16 + r;
                    const bool ca = key <= t;
                    const bool wi = ca && (t - key) < kWIN;
                    const float e1 = wi ? __expf(acc[kt][r] - mWn) : 0.f;
                    sumW += e1;
                    hw[kt] = (_Float16)e1;
                }
                *(half4v*)&PW[l15 * kPSt + 16 * quad + 4 * r] = hw;
            }
        }
        sumS += __shfl_xor(sumS, 16);
        sumS += __shfl_xor(sumS, 32);
        sumW += __shfl_xor(sumW, 16);
        sumW += __shfl_xor(sumW, 32);
        if (bsel) { lS = lS * aS + sumS; mS = mSn; }
        if (bswa) { lW = lW * aW + sumW; mW = mWn; }

        float aSh[4], aWh[4];
        #pragma unroll
        for (int r = 0; r < 4; ++r) {
            aSh[r] = __shfl(aS, quad * 4 + r);
            aWh[r] = __shfl(aW, quad * 4 + r);
        }

        half8 apS0, apS1, apW0, apW1;
        if (bsel) {
            apS0 = *(const half8*)&PS[l15 * kPSt + quad * 8];
            apS1 = *(const half8*)&PS[l15 * kPSt + 32 + quad * 8];
        }
        if (bswa) {
            apW0 = *(const half8*)&PW[l15 * kPSt + quad * 8];
            apW1 = *(const half8*)&PW[l15 * kPSt + 32 + quad * 8];
        }

        #pragma unroll
        for (int n8 = 0; n8 < 8; ++n8) {
            if (bsel) {
                #pragma unroll
                for (int r = 0; r < 4; ++r) osel[n8][r] *= aSh[r];
                osel[n8] = __builtin_amdgcn_mfma_f32_16x16x32_f16(apS0, vreg[n8][0], osel[n8], 0, 0, 0);
                osel[n8] = __builtin_amdgcn_mfma_f32_16x16x32_f16(apS1, vreg[n8][1], osel[n8], 0, 0, 0);
            }
            if (bswa) {
                #pragma unroll
                for (int r = 0; r < 4; ++r) oswa[n8][r] *= aWh[r];
                oswa[n8] = __builtin_amdgcn_mfma_f32_16x16x32_f16(apW0, vreg[n8][0], oswa[n8], 0, 0, 0);
                oswa[n8] = __builtin_amdgcn_mfma_f32_16x16x32_f16(apW1, vreg[n8][1], oswa[n8], 0, 0, 0);
            }
        }
    }

    // ---- merged epilogue: single store, cmp read from stash ----
    const float lsI = 1.f / lS;
    const float lwI = 1.f / lW;
    #pragma unroll
    for (int r = 0; r < 4; ++r) {
        const int h = quad * 4 + r;
        const float lsH = __shfl(lsI, h);
        const float lwH = __shfl(lwI, h);
        const float c0 = cw[((size_t)t * kHQ + h) * 3 + 0];
        const float c1 = cw[((size_t)t * kHQ + h) * 3 + 1];
        const float c2 = cw[((size_t)t * kHQ + h) * 3 + 2];
        const float w0 = 1.f / (1.f + __expf(-c0));
        const float w1 = 1.f / (1.f + __expf(-c1));
        const float w2 = 1.f / (1.f + __expf(-c2));
        float* op = out + ((size_t)t * kHQ + h) * kD + l15;
        #pragma unroll
        for (int n8 = 0; n8 < 8; ++n8) {
            const float oc = b2f(ocst[lane * kOC + n8 * 4 + r]);
            op[n8 * 16] = w0 * oc + w1 * osel[n8][r] * lsH + w2 * oswa[n8][r] * lwH;
        }
    }
}

// ---------------------------------------------------------------------
extern "C" void kernel_launch(void* const* d_in, const int* in_sizes, int n_in,
                              void* d_out, int out_size, void* d_ws, size_t ws_size,
                              hipStream_t stream) {
    const float* q  = (const float*)d_in[0];
    const float* k  = (const float*)d_in[1];
    const float* v  = (const float*)d_in[2];
    const float* cw = (const float*)d_in[3];
    float* out = (float*)d_out;

    short* cmp_kh = (short*)d_ws;                        // 128*128 bf16 hi
    short* cmp_kl = cmp_kh + 128 * kD;                   // 128*128 bf16 lo
    short* cvt    = cmp_kl + 128 * kD;                   // 128*128 bf16 (perm)
    short* kb     = cvt + 128 * 128;                     // kKBRows*kD bf16
    _Float16* vt  = (_Float16*)(kb + (size_t)kKBRows * kD);  // kD*kVTCols fp16

    k_stage<<<dim3(kKBRows + 128), dim3(kD), 0, stream>>>(k, v, kb, vt, cmp_kh, cmp_kl, cvt);
    k_nsa<<<dim3(kT), dim3(64), 0, stream>>>(q, cw, cmp_kh, cmp_kl, cvt, kb, vt, out);
}

// Round 7
// 215.592 us; speedup vs baseline: 1.5992x; 1.5992x over previous
//
#include <hip/hip_runtime.h>
#include <math.h>

// ---- NSA hyperparameters (compile-time, matches reference config) ----
constexpr int kT    = 2048;
constexpr int kHQ   = 16;
constexpr int kD    = 128;
constexpr int kKS   = 32;
constexpr int kST   = 16;
constexpr int kBS   = 64;
constexpr int kM    = (kT - kKS) / kST + 1;   // 127 compressed tokens
constexpr int kNB   = (kT + kBS - 1) / kBS;   // 32 selection blocks
constexpr int kTopN = 16;
constexpr int kNInit = 2;
constexpr int kWIN  = 512;
constexpr float kNEG = -1e30f;
constexpr float kScale = 0.08838834764831845f; // 128^-0.5

constexpr int kPad    = 32;
constexpr int kKBRows = kT + kPad; // 2080
constexpr int kVTCols = kT + kPad; // 2080

constexpr int kPSt = 72;    // P slab row stride (fp16)
constexpr int kPL  = 136;   // cmp p_lds row stride (bf16 shorts)
constexpr int kOC  = 36;    // ocmp stash lane stride (shorts; 72B, 8B-aligned)

typedef __attribute__((ext_vector_type(8))) short short8;
typedef __attribute__((ext_vector_type(4))) short short4v;
typedef __attribute__((ext_vector_type(8))) _Float16 half8;
typedef __attribute__((ext_vector_type(4))) _Float16 half4v;
typedef __attribute__((ext_vector_type(4))) float floatx4;

// RNE float -> bf16 bits
__device__ inline short f2bf(float x) {
    unsigned u = __float_as_uint(x);
    unsigned r = (u + 0x7fffu + ((u >> 16) & 1u)) >> 16;
    return (short)r;
}
__device__ inline float b2f(short h) {
    return __uint_as_float(((unsigned)(unsigned short)h) << 16);
}

// ---------------------------------------------------------------------
// K1: staging.  blocks [0,2080): bf16 K rows + fp16 V^T cols with the
// swapped-QK key permutation col = 4*(w&15) + (w>>4) (w = key mod 64).
// Pad rows (row >= kT) do NOT write vt (R3 lesson: perm overflows pad).
// blocks [2080,2208): mean-pool cmp_k as bf16 hi/lo planes + cmp V^T
// bf16 with the same permutation over m.  block=(128)
// ---------------------------------------------------------------------
__global__ void k_stage(const float* __restrict__ k, const float* __restrict__ v,
                        short* __restrict__ kb, _Float16* __restrict__ vt,
                        short* __restrict__ cmp_kh, short* __restrict__ cmp_kl,
                        short* __restrict__ cvt) {
    const int bid = blockIdx.x;
    const int d = threadIdx.x;
    if (bid < kKBRows) {
        const int row = bid;
        if (row < kT) {
            const int blk = row >> 6, w = row & 63;
            const int col = blk * kBS + 4 * (w & 15) + (w >> 4);
            kb[row * kD + d] = f2bf(k[(size_t)row * kD + d]);
            vt[(size_t)d * kVTCols + col] = (_Float16)v[(size_t)row * kD + d];
        } else {
            kb[row * kD + d] = 0;   // in-bounds, never read
        }
    } else {
        const int m = bid - kKBRows;        // 0..127 (>=kM = zero pad)
        float sk = 0.f, sv = 0.f;
        if (m < kM) {
            const int base = m * kST;
            #pragma unroll
            for (int i = 0; i < kKS; ++i) {
                sk += k[(size_t)(base + i) * kD + d];
                sv += v[(size_t)(base + i) * kD + d];
            }
            sk *= (1.0f / kKS);
            sv *= (1.0f / kKS);
        }
        const short hi = f2bf(sk);
        cmp_kh[m * kD + d] = hi;
        cmp_kl[m * kD + d] = f2bf(sk - b2f(hi));
        const int pc = (m & 64) + 4 * (m & 15) + ((m & 63) >> 4);
        cvt[d * 128 + pc] = f2bf(sv);
    }
}

// ---------------------------------------------------------------------
// Fused NSA kernel: one WAVE = one query t (grid=T, block=64, t=bid).
// __launch_bounds__(64,1) is ESSENTIAL: without it hipcc assumes
// 1024-thread blocks and caps VGPRs at 64 -> catastrophic spilling
// (R6: 646 MB scratch traffic).  R4's (64,1) measured 136 VGPR clean.
// Phase A (cmp-attn): swapped-QK MFMA, bf16 hi/lo split, lane-local
//   softmax, butterfly slc_p, rank top-k in registers.  ocmp stashed to
//   LDS as bf16 (frees 32 VGPRs for Phase B — R5 spill lesson).
// Phase B: R4-proven inline body, single K buffer.
// Epilogue: merged single store reading the stash.
// ---------------------------------------------------------------------
__global__ __launch_bounds__(64, 1) void k_nsa(
        const float* __restrict__ q, const float* __restrict__ cw,
        const short* __restrict__ cmp_kh, const short* __restrict__ cmp_kl,
        const short* __restrict__ cvt, const short* __restrict__ kb,
        const _Float16* __restrict__ vt, float* __restrict__ out) {
    const int lane = threadIdx.x;
    const int l15 = lane & 15;
    const int quad = lane >> 4;
    const int t = blockIdx.x;

    __shared__ float sp[kNB];
    __shared__ short p_lds[16 * kPL];       // cmp P, bf16, perm cols
    __shared__ short ocst[64 * kOC];        // ocmp stash, bf16
    __shared__ _Float16 PS[16 * kPSt];
    __shared__ _Float16 PW[16 * kPSt];

    // ---- q head=l15, scaled, split hi/lo bf16 ----
    short8 qh[4], ql[4];
    {
        const float* qp = q + ((size_t)t * kHQ + l15) * kD + quad * 8;
        #pragma unroll
        for (int c = 0; c < 4; ++c) {
            const float4 f0 = *(const float4*)(qp + c * 32);
            const float4 f1 = *(const float4*)(qp + c * 32 + 4);
            const float xs[8] = {f0.x, f0.y, f0.z, f0.w, f1.x, f1.y, f1.z, f1.w};
            #pragma unroll
            for (int j = 0; j < 8; ++j) {
                const float x = xs[j] * kScale;
                const short h = f2bf(x);
                qh[c][j] = h;
                ql[c][j] = f2bf(x - b2f(h));
            }
        }
    }

    const int nvalid = (t >= kKS - 1) ? min(kM, (t - (kKS - 1)) / kST + 1) : 0;
    const int cur = t >> 6;

    // ================= Phase A: compressed attention =================
    unsigned selm;
    {
        floatx4 sacc[8];
        #pragma unroll
        for (int mt = 0; mt < 8; ++mt) {
            sacc[mt] = (floatx4){0, 0, 0, 0};
            const short* ah = cmp_kh + (mt * 16 + l15) * 128 + quad * 8;
            const short* al = cmp_kl + (mt * 16 + l15) * 128 + quad * 8;
            #pragma unroll
            for (int c = 0; c < 4; ++c) {
                const short8 Ah = *(const short8*)(ah + c * 32);
                const short8 Al = *(const short8*)(al + c * 32);
                sacc[mt] = __builtin_amdgcn_mfma_f32_16x16x32_bf16(Ah, qh[c], sacc[mt], 0, 0, 0);
                sacc[mt] = __builtin_amdgcn_mfma_f32_16x16x32_bf16(Ah, ql[c], sacc[mt], 0, 0, 0);
                sacc[mt] = __builtin_amdgcn_mfma_f32_16x16x32_bf16(Al, qh[c], sacc[mt], 0, 0, 0);
            }
        }
        // lane holds S[m = mt*16 + quad*4 + r][h = l15]
        float e[8][4];
        float mx = kNEG;
        #pragma unroll
        for (int mt = 0; mt < 8; ++mt)
            #pragma unroll
            for (int r = 0; r < 4; ++r) {
                const int m = mt * 16 + quad * 4 + r;
                const float s = (m < nvalid) ? sacc[mt][r] : kNEG;
                e[mt][r] = s;
                mx = fmaxf(mx, s);
            }
        mx = fmaxf(mx, __shfl_xor(mx, 16));
        mx = fmaxf(mx, __shfl_xor(mx, 32));
        float sum = 0.f;
        #pragma unroll
        for (int mt = 0; mt < 8; ++mt)
            #pragma unroll
            for (int r = 0; r < 4; ++r) {
                const int m = mt * 16 + quad * 4 + r;
                const float ev = (m < nvalid) ? __expf(e[mt][r] - mx) : 0.f;
                e[mt][r] = ev;
                sum += ev;
            }
        sum += __shfl_xor(sum, 16);
        sum += __shfl_xor(sum, 32);
        const float inv = (nvalid > 0) ? (1.f / sum) : 0.f;

        float Z[8], Y[8];
        #pragma unroll
        for (int mt = 0; mt < 8; ++mt) {
            const float p0 = e[mt][0] * inv, p1 = e[mt][1] * inv;
            const float p2 = e[mt][2] * inv, p3 = e[mt][3] * inv;
            e[mt][0] = p0; e[mt][1] = p1; e[mt][2] = p2; e[mt][3] = p3;
            Z[mt] = p0 + p1 + p2 + 0.5f * p3;
            Y[mt] = p3;
        }
        // p -> LDS (bf16, perm col = g*64 + 16*quad + 4*r + (mt&3))
        #pragma unroll
        for (int g = 0; g < 2; ++g)
            #pragma unroll
            for (int r = 0; r < 4; ++r) {
                short4v s4;
                s4[0] = f2bf(e[4 * g + 0][r]); s4[1] = f2bf(e[4 * g + 1][r]);
                s4[2] = f2bf(e[4 * g + 2][r]); s4[3] = f2bf(e[4 * g + 3][r]);
                *(short4v*)&p_lds[l15 * kPL + g * 64 + 16 * quad + 4 * r] = s4;
            }
        // butterfly h-sums (over l15 within each quad group)
        #pragma unroll
        for (int mt = 0; mt < 8; ++mt) {
            #pragma unroll
            for (int o = 1; o <= 8; o <<= 1) {
                Z[mt] += __shfl_xor(Z[mt], o, 16);
                Y[mt] += __shfl_xor(Y[mt], o, 16);
            }
        }
        // x[b = 4*mt + quad] = Z + 0.5 * Y(prev block)
        const int srcl = ((quad + 3) & 3) * 16 + l15;
        #pragma unroll
        for (int mt = 0; mt < 8; ++mt) {
            const float up  = __shfl(Y[mt], srcl);
            const float upm = __shfl(Y[(mt + 7) & 7], srcl);
            const float pv = quad ? up : (mt ? upm : 0.f);
            const int b = 4 * mt + quad;
            float x = Z[mt] + 0.5f * pv;
            if (b > cur) x = kNEG;
            if (b < kNInit || b == cur) x = 1e30f;
            if (l15 == 0) sp[b] = x;
        }
        // rank top-k (serial-argmax tie semantics; R4-proven)
        bool selp = false;
        if (lane < kNB) {
            const float xv = sp[lane];
            int rank = 0;
            #pragma unroll
            for (int b2 = 0; b2 < kNB; ++b2) {
                const float y = sp[b2];
                rank += (y > xv || (y == xv && b2 < lane)) ? 1 : 0;
            }
            selp = rank < kTopN;
        }
        selm = (unsigned)__ballot(selp);

        // cmp PV -> stash to LDS as bf16 (same-lane, no barrier needed)
        short8 ap[4];
        #pragma unroll
        for (int c = 0; c < 4; ++c)
            ap[c] = *(const short8*)&p_lds[l15 * kPL + c * 32 + quad * 8];
        #pragma unroll
        for (int nt = 0; nt < 8; ++nt) {
            floatx4 oc = (floatx4){0, 0, 0, 0};
            #pragma unroll
            for (int c = 0; c < 4; ++c) {
                const short8 bv = *(const short8*)(cvt + (size_t)(nt * 16 + l15) * 128 + c * 32 + quad * 8);
                oc = __builtin_amdgcn_mfma_f32_16x16x32_bf16(ap[c], bv, oc, 0, 0, 0);
            }
            short4v s4;
            s4[0] = f2bf(oc[0]); s4[1] = f2bf(oc[1]);
            s4[2] = f2bf(oc[2]); s4[3] = f2bf(oc[3]);
            *(short4v*)&ocst[lane * kOC + nt * 4] = s4;
        }
    }

    // ================= Phase B: select + SWA (R4-proven, inline) ======
    const int lob = max(0, (t - (kWIN - 1)) >> 6);
    const unsigned lm = 0xFFFFFFFFu >> (31 - cur);
    unsigned act = (selm & lm) | (lm & ~((1u << lob) - 1u));

    float mS = kNEG, lS = 0.f, mW = kNEG, lW = 0.f;
    floatx4 osel[8], oswa[8];
    #pragma unroll
    for (int n8 = 0; n8 < 8; ++n8) {
        osel[n8] = (floatx4){0, 0, 0, 0};
        oswa[n8] = (floatx4){0, 0, 0, 0};
    }

    while (act) {
        const int b = __builtin_ctz(act);
        act &= act - 1u;
        const bool bsel = (selm >> b) & 1u;
        const bool bswa = b >= lob;

        short8 kreg[4][4];
        {
            const short* kp = kb + (size_t)(b * kBS + l15) * kD + quad * 8;
            #pragma unroll
            for (int kt = 0; kt < 4; ++kt)
                #pragma unroll
                for (int c = 0; c < 4; ++c)
                    kreg[kt][c] = *(const short8*)(kp + kt * 16 * kD + c * 32);
        }
        half8 vreg[8][2];
        {
            const _Float16* vp = vt + (size_t)l15 * kVTCols + b * kBS + quad * 8;
            #pragma unroll
            for (int n8 = 0; n8 < 8; ++n8) {
                vreg[n8][0] = *(const half8*)(vp + (size_t)(n8 * 16) * kVTCols);
                vreg[n8][1] = *(const half8*)(vp + (size_t)(n8 * 16) * kVTCols + 32);
            }
        }

        floatx4 acc[4];
        #pragma unroll
        for (int kt = 0; kt < 4; ++kt) {
            acc[kt] = (floatx4){0, 0, 0, 0};
            #pragma unroll
            for (int c = 0; c < 4; ++c)
                acc[kt] = __builtin_amdgcn_mfma_f32_16x16x32_bf16(kreg[kt][c], qh[c], acc[kt], 0, 0, 0);
        }

        const int kbase = b * kBS + quad * 4;
        float bmS = kNEG, bmW = kNEG;
        #pragma unroll
        for (int kt = 0; kt < 4; ++kt)
            #pragma unroll
            for (int r = 0; r < 4; ++r) {
                const int key = kbase + kt * 16 + r;
                const float s = acc[kt][r];
                const bool ca = key <= t;
                const bool wi = ca && (t - key) < kWIN;
                if (ca) bmS = fmaxf(bmS, s);
                if (wi) bmW = fmaxf(bmW, s);
            }
        bmS = fmaxf(bmS, __shfl_xor(bmS, 16));
        bmS = fmaxf(bmS, __shfl_xor(bmS, 32));
        bmW = fmaxf(bmW, __shfl_xor(bmW, 16));
        bmW = fmaxf(bmW, __shfl_xor(bmW, 32));

        float aS = 1.f, aW = 1.f;
        float mSn = mS, mWn = mW;
        if (bsel) { mSn = fmaxf(mS, bmS); aS = __expf(mS - mSn); }
        if (bswa) { mWn = fmaxf(mW, bmW); aW = __expf(mW - mWn); }

        float sumS = 0.f, sumW = 0.f;
        if (bsel && bswa) {
            const float crv = __expf(mSn - mWn);
            #pragma unroll
            for (int r = 0; r < 4; ++r) {
                half4v hs, hw;
                #pragma unroll
                for (int kt = 0; kt < 4; ++kt) {
                    const int key = kbase + kt * 16 + r;
                    const bool ca = key <= t;
                    const bool wi = ca && (t - key) < kWIN;
                    const float e0 = ca ? __expf(acc[kt][r] - mSn) : 0.f;
                    const float e1 = wi ? e0 * crv : 0.f;
                    sumS += e0; sumW += e1;
                    hs[kt] = (_Float16)e0;
                    hw[kt] = (_Float16)e1;
                }
                *(half4v*)&PS[l15 * kPSt + 16 * quad + 4 * r] = hs;
                *(half4v*)&PW[l15 * kPSt + 16 * quad + 4 * r] = hw;
            }
        } else if (bsel) {
            #pragma unroll
            for (int r = 0; r < 4; ++r) {
                half4v hs;
                #pragma unroll
                for (int kt = 0; kt < 4; ++kt) {
                    const int key = kbase + kt * 16 + r;
                    const bool ca = key <= t;
                    const float e0 = ca ? __expf(acc[kt][r] - mSn) : 0.f;
                    sumS += e0;
                    hs[kt] = (_Float16)e0;
                }
                *(half4v*)&PS[l15 * kPSt + 16 * quad + 4 * r] = hs;
            }
        } else {
            #pragma unroll
            for (int r = 0; r < 4; ++r) {
                half4v hw;
                #pragma unroll
                for (int kt = 0; kt < 4; ++kt) {
                    const int key = kbase + kt * 16 + r;
                    const bool ca = key <= t;
                    const bool wi = ca && (t - key) < kWIN;
                    const float e1 = wi ? __expf(acc[kt][r] - mWn) : 0.f;
                    sumW += e1;
                    hw[kt] = (_Float16)e1;
                }
                *(half4v*)&PW[l15 * kPSt + 16 * quad + 4 * r] = hw;
            }
        }
        sumS += __shfl_xor(sumS, 16);
        sumS += __shfl_xor(sumS, 32);
        sumW += __shfl_xor(sumW, 16);
        sumW += __shfl_xor(sumW, 32);
        if (bsel) { lS = lS * aS + sumS; mS = mSn; }
        if (bswa) { lW = lW * aW + sumW; mW = mWn; }

        float aSh[4], aWh[4];
        #pragma unroll
        for (int r = 0; r < 4; ++r) {
            aSh[r] = __shfl(aS, quad * 4 + r);
            aWh[r] = __shfl(aW, quad * 4 + r);
        }

        half8 apS0, apS1, apW0, apW1;
        if (bsel) {
            apS0 = *(const half8*)&PS[l15 * kPSt + quad * 8];
            apS1 = *(const half8*)&PS[l15 * kPSt + 32 + quad * 8];
        }
        if (bswa) {
            apW0 = *(const half8*)&PW[l15 * kPSt + quad * 8];
            apW1 = *(const half8*)&PW[l15 * kPSt + 32 + quad * 8];
        }

        #pragma unroll
        for (int n8 = 0; n8 < 8; ++n8) {
            if (bsel) {
                #pragma unroll
                for (int r = 0; r < 4; ++r) osel[n8][r] *= aSh[r];
                osel[n8] = __builtin_amdgcn_mfma_f32_16x16x32_f16(apS0, vreg[n8][0], osel[n8], 0, 0, 0);
                osel[n8] = __builtin_amdgcn_mfma_f32_16x16x32_f16(apS1, vreg[n8][1], osel[n8], 0, 0, 0);
            }
            if (bswa) {
                #pragma unroll
                for (int r = 0; r < 4; ++r) oswa[n8][r] *= aWh[r];
                oswa[n8] = __builtin_amdgcn_mfma_f32_16x16x32_f16(apW0, vreg[n8][0], oswa[n8], 0, 0, 0);
                oswa[n8] = __builtin_amdgcn_mfma_f32_16x16x32_f16(apW1, vreg[n8][1], oswa[n8], 0, 0, 0);
            }
        }
    }

    // ---- merged epilogue: single store, cmp read from stash ----
    const float lsI = 1.f / lS;
    const float lwI = 1.f / lW;
    #pragma unroll
    for (int r = 0; r < 4; ++r) {
        const int h = quad * 4 + r;
        const float lsH = __shfl(lsI, h);
        const float lwH = __shfl(lwI, h);
        const float c0 = cw[((size_t)t * kHQ + h) * 3 + 0];
        const float c1 = cw[((size_t)t * kHQ + h) * 3 + 1];
        const float c2 = cw[((size_t)t * kHQ + h) * 3 + 2];
        const float w0 = 1.f / (1.f + __expf(-c0));
        const float w1 = 1.f / (1.f + __expf(-c1));
        const float w2 = 1.f / (1.f + __expf(-c2));
        float* op = out + ((size_t)t * kHQ + h) * kD + l15;
        #pragma unroll
        for (int n8 = 0; n8 < 8; ++n8) {
            const float oc = b2f(ocst[lane * kOC + n8 * 4 + r]);
            op[n8 * 16] = w0 * oc + w1 * osel[n8][r] * lsH + w2 * oswa[n8][r] * lwH;
        }
    }
}

// ---------------------------------------------------------------------
extern "C" void kernel_launch(void* const* d_in, const int* in_sizes, int n_in,
                              void* d_out, int out_size, void* d_ws, size_t ws_size,
                              hipStream_t stream) {
    const float* q  = (const float*)d_in[0];
    const float* k  = (const float*)d_in[1];
    const float* v  = (const float*)d_in[2];
    const float* cw = (const float*)d_in[3];
    float* out = (float*)d_out;

    short* cmp_kh = (short*)d_ws;                        // 128*128 bf16 hi
    short* cmp_kl = cmp_kh + 128 * kD;                   // 128*128 bf16 lo
    short* cvt    = cmp_kl + 128 * kD;                   // 128*128 bf16 (perm)
    short* kb     = cvt + 128 * 128;                     // kKBRows*kD bf16
    _Float16* vt  = (_Float16*)(kb + (size_t)kKBRows * kD);  // kD*kVTCols fp16

    k_stage<<<dim3(kKBRows + 128), dim3(kD), 0, stream>>>(k, v, kb, vt, cmp_kh, cmp_kl, cvt);
    k_nsa<<<dim3(kT), dim3(64), 0, stream>>>(q, cw, cmp_kh, cmp_kl, cvt, kb, vt, out);
}